// Round 14
// baseline (677.980 us; speedup 1.0000x reference)
//
#include <hip/hip_runtime.h>
#include <hip/hip_bf16.h>

#define T_STEPS 2048
#define BATCH   256
#define DIM     128
#define INV2PI  0.15915494309189535f
#define NEG2LOG2E  -2.885390082f      // -2/ln2: tanh(c)=2*rcp(1+exp2(c*NEG2LOG2E))-1
#define NEGHALFLN2 -0.34657359028f    // 1/NEG2LOG2E: recover c from scaled state

#define ZX_FLOATS (T_STEPS * BATCH * 16)   // 33.5 MB

// ---------------------------------------------------------------------------
// prep (R12 verbatim): unit-major lane layout u = k*4+g.
// Wc[d*16 + (k*4+g)] = W_g[d*4+k]/2pi, bt[k*4+g] = (b_g[k]+theta_g[k])/2pi.
// ---------------------------------------------------------------------------
__global__ __launch_bounds__(64) void prep(
    const float* __restrict__ Wf, const float* __restrict__ bf, const float* __restrict__ tf,
    const float* __restrict__ Wi, const float* __restrict__ bi, const float* __restrict__ ti,
    const float* __restrict__ Wu, const float* __restrict__ bu, const float* __restrict__ tu,
    const float* __restrict__ Wo, const float* __restrict__ bo, const float* __restrict__ to_,
    float* __restrict__ Wc, float* __restrict__ bt)
{
    const int tid = threadIdx.x;
    for (int idx = tid; idx < DIM * 16; idx += 64) {
        int d = idx >> 4, u = idx & 15, g = u & 3, k = u >> 2;
        const float* W = (g == 0) ? Wf : (g == 1) ? Wi : (g == 2) ? Wu : Wo;
        Wc[idx] = W[d * 4 + k] * INV2PI;
    }
    if (tid < 16) {
        int g = tid & 3, k = tid >> 2;
        const float* bb = (g == 0) ? bf : (g == 1) ? bi : (g == 2) ? bu : bo;
        const float* tt = (g == 0) ? tf : (g == 1) ? ti : (g == 2) ? tu : to_;
        bt[tid] = (bb[k] + tt[k]) * INV2PI;
    }
}

// ---------------------------------------------------------------------------
// Kernel 1 v8: v5 + cross-chunk software pipeline. v5 exposed ~900cyc global
// latency per chunk ({load,write,read,FMA} serial; 102us = 2.6TB/s << BW
// ceiling => latency-bound). v8 per chunk: {read xr_c (whole slice to regs,
// tile then dead) -> write c+1 (its loads flew under FMA c-1) -> issue loads
// c+2 -> FMA c}. In-order per-wave DS makes the tile overwrite race-free;
// only the prologue (~1800cyc) is exposed. FMA order over (c,dd,u) is
// BIT-IDENTICAL to v5/R12. ~90 VGPR -> still 4 waves/SIMD, 4 blocks/CU.
// ---------------------------------------------------------------------------
__global__ __launch_bounds__(256) void zx_gemm(
    const float4* __restrict__ x4,
    const float*  __restrict__ Wc,    // [128][16] packed, prescaled
    const float*  __restrict__ btv,   // [16] prescaled
    float4*       __restrict__ Zx4)
{
    __shared__ float xs[4][64 * 36];          // 36864 B total
    const int lane = threadIdx.x & 63;
    const int wid  = threadIdx.x >> 6;
    float* myxs = xs[wid];
    const size_t wrow0 = ((size_t)blockIdx.x * 4 + wid) * 64;

    float acc[16];
#pragma unroll
    for (int u = 0; u < 16; ++u) acc[u] = btv[u];   // uniform -> s_load

    const int r0 = lane >> 3;                 // 0..7
    const int q  = lane & 7;                  // 0..7

    float4 v[8];
    auto gload = [&](int c) {
#pragma unroll
        for (int i = 0; i < 8; ++i)
            v[i] = x4[(wrow0 + i * 8 + r0) * 32 + c * 8 + q];
    };
    auto lwrite = [&]() {
#pragma unroll
        for (int i = 0; i < 8; ++i)
            *(float4*)&myxs[(i * 8 + r0) * 36 + q * 4] = v[i];
    };

    gload(0);
    lwrite();                                 // stage chunk 0 (prologue wait)
    gload(1);                                 // chunk 1 in flight

#pragma unroll
    for (int c = 0; c < 4; ++c) {
        float xr[32];
#pragma unroll
        for (int j = 0; j < 8; ++j) {
            float4 tv = *(const float4*)&myxs[lane * 36 + j * 4];
            xr[j * 4 + 0] = tv.x; xr[j * 4 + 1] = tv.y;
            xr[j * 4 + 2] = tv.z; xr[j * 4 + 3] = tv.w;
        }
        if (c < 3) lwrite();                  // stage c+1 (loads already landed)
        if (c < 2) gload(c + 2);              // fly under FMA below
#pragma unroll
        for (int dd = 0; dd < 32; ++dd) {
            const float xv = xr[dd];
            const float* w = &Wc[(c * 32 + dd) * 16]; // uniform -> s_load
#pragma unroll
            for (int u = 0; u < 16; ++u) acc[u] = fmaf(xv, w[u], acc[u]);
        }
    }

    size_t orow = wrow0 + lane;
    float4* zr = &Zx4[orow * 4];
    zr[0] = make_float4(acc[0],  acc[1],  acc[2],  acc[3]);
    zr[1] = make_float4(acc[4],  acc[5],  acc[6],  acc[7]);
    zr[2] = make_float4(acc[8],  acc[9],  acc[10], acc[11]);
    zr[3] = make_float4(acc[12], acc[13], acc[14], acc[15]);
}

// ---------------------------------------------------------------------------
// Kernel 2 v6: R12 unit-major rec + scaled-c. The chain stage c -> c*(-2.885)
// -> exp2 is cut by tracking cs_ = -2.885*c: the update becomes
// cs_ = fmaf(fv, cs_, (iv*gv)*NEG2LOG2E) (extra mul is OFF the chain), and
// exp2 consumes cs_ directly. True c recovered only at t=2047 for output.
// Everything else verbatim (300 -> ~285 cyc/step predicted).
// ---------------------------------------------------------------------------
template<int CTRL, bool BC>
__device__ __forceinline__ float fdpp2(float old, float x) {
    return __int_as_float(__builtin_amdgcn_update_dpp(
        __float_as_int(old), __float_as_int(x), CTRL, 0xF, 0xF, BC));
}
template<int CTRL>
__device__ __forceinline__ float fdpp(float x) {
    return __int_as_float(__builtin_amdgcn_update_dpp(
        0, __float_as_int(x), CTRL, 0xF, 0xF, true));
}

__device__ __forceinline__ float lstm_step(
    float& h, float& cs_, float& cm1, float& cm2, float& cm3, float zb,
    float whr0, float whr1, float whr2, float whr3,
    float s1c, float m2, float m3)
{
    float za  = fmaf(h, whr0, zb);
    float hr1 = fdpp<0x124>(h);               // row_ror:4  -> h[(k-1)&3]
    float hr2 = fdpp<0x128>(h);               // row_ror:8  -> h[(k-2)&3]
    float hr3 = fdpp<0x12C>(h);               // row_ror:12 -> h[(k-3)&3]
    float t1  = fmaf(hr2, whr2, hr3 * whr3);
    float z   = fmaf(hr1, whr1, za) + t1;     // in revolutions

    float cs = __builtin_amdgcn_cosf(__builtin_amdgcn_fractf(z));

    // persistent-old masked shifts: invalid lanes (k<j) keep their seeded 1.0
    cm1 = fdpp2<0x114, false>(cm1, cs);       // row_shr:4  -> cos[k-1]
    cm2 = fdpp2<0x118, false>(cm2, cs);       // row_shr:8  -> cos[k-2]
    cm3 = fdpp2<0x11C, false>(cm3, cs);       // row_shr:12 -> cos[k-3]
    float p = (cs * cm1) * (cm2 * cm3);

    float e = __builtin_amdgcn_exp2f(p * s1c);
    float y = fmaf(__builtin_amdgcn_rcpf(1.f + e), m2, m3);

    float fv = fdpp<0x00>(y);                 // quad lane 0 = forget
    float iv = fdpp<0x55>(y);                 // quad lane 1 = input
    float gv = fdpp<0xAA>(y);                 // quad lane 2 = update
    float ov = fdpp<0xFF>(y);                 // quad lane 3 = output

    cs_ = fmaf(fv, cs_, (iv * gv) * NEG2LOG2E);   // scaled cell state
    float e2 = __builtin_amdgcn_exp2f(cs_);
    float th = fmaf(2.f, __builtin_amdgcn_rcpf(1.f + e2), -1.f);
    h = ov * th;
    return h;
}

__global__ __launch_bounds__(64) void qlstm_rec(
    const float* __restrict__ Zx,
    const float* __restrict__ Wf, const float* __restrict__ Wi,
    const float* __restrict__ Wu, const float* __restrict__ Wo,
    float* __restrict__ out)
{
    const int tid = threadIdx.x;
    const int u   = tid & 15;
    const int g   = u & 3;                    // unit-major layout
    const int k   = u >> 2;
    const int b   = blockIdx.x * 4 + (tid >> 4);   // 64 blocks x 4 batches

    const float* Wg = (g == 0) ? Wf : (g == 1) ? Wi : (g == 2) ? Wu : Wo;
    // whr[j] pairs with h[(k-j)&3] (row_ror:4j under dst[i]=src[i-N])
    const float whr0 = Wg[(DIM + k)             * 4 + k] * INV2PI;
    const float whr1 = Wg[(DIM + ((k + 3) & 3)) * 4 + k] * INV2PI;
    const float whr2 = Wg[(DIM + ((k + 2) & 3)) * 4 + k] * INV2PI;
    const float whr3 = Wg[(DIM + ((k + 1) & 3)) * 4 + k] * INV2PI;

    const bool  isg = (g == 2);
    const float s1c = isg ? -2.885390082f : -1.442695041f;
    const float m2  = isg ? 2.f : 1.f;
    const float m3  = isg ? -1.f : 0.f;

    const float* zp = Zx + b * 16 + u;      // step stride B*16 = 4096
    const bool do_store = (g == 0);         // lanes 0,4,8,12: write unit k
    float* op = out + b * 4 + k;

    float h = 0.f, cs_ = 0.f;               // cs_ = c * NEG2LOG2E (c=0 -> 0)
    float cm1 = 1.f, cm2 = 1.f, cm3 = 1.f;  // persistent masked-DPP registers

    float zv[8];
#pragma unroll
    for (int i = 0; i < 8; ++i) zv[i] = zp[(size_t)i * 4096];

    for (int t = 0; t < T_STEPS; t += 8) {
#pragma unroll
        for (int j = 0; j < 8; ++j) {
            int tt = t + j;

            float o = lstm_step(h, cs_, cm1, cm2, cm3, zv[j],
                                whr0, whr1, whr2, whr3, s1c, m2, m3);

            if (do_store) op[(size_t)tt * (BATCH * 4)] = o;

            int tn = tt + 8;
            if (tn > T_STEPS - 1) tn = T_STEPS - 1;
            zv[j] = zp[(size_t)tn * 4096];
        }
    }

    if (do_store) {
        size_t hx_off = (size_t)T_STEPS * BATCH * 4;
        out[hx_off + b * 4 + k] = h;
        out[hx_off + BATCH * 4 + b * 4 + k] = cs_ * NEGHALFLN2;  // recover c
    }
}

extern "C" void kernel_launch(void* const* d_in, const int* in_sizes, int n_in,
                              void* d_out, int out_size, void* d_ws, size_t ws_size,
                              hipStream_t stream) {
    const float* x  = (const float*)d_in[0];
    const float* Wf = (const float*)d_in[1];
    const float* bf = (const float*)d_in[2];
    const float* tf = (const float*)d_in[3];
    const float* Wi = (const float*)d_in[4];
    const float* bi = (const float*)d_in[5];
    const float* ti = (const float*)d_in[6];
    const float* Wu = (const float*)d_in[7];
    const float* bu = (const float*)d_in[8];
    const float* tu = (const float*)d_in[9];
    const float* Wo = (const float*)d_in[10];
    const float* bo = (const float*)d_in[11];
    const float* to_ = (const float*)d_in[12];
    float* out = (float*)d_out;

    float* Zx = (float*)d_ws;                       // 33.5 MB
    float* Wc = Zx + ZX_FLOATS;                     // 8 KB
    float* bt = Wc + DIM * 16;                      // 64 B

    prep<<<1, 64, 0, stream>>>(Wf, bf, tf, Wi, bi, ti, Wu, bu, tu, Wo, bo, to_, Wc, bt);

    zx_gemm<<<(T_STEPS * BATCH) / 256, 256, 0, stream>>>(
        (const float4*)x, Wc, bt, (float4*)Zx);

    qlstm_rec<<<BATCH / 4, 64, 0, stream>>>(Zx, Wf, Wi, Wu, Wo, out);
}